// Round 1
// 426.118 us; speedup vs baseline: 1.0107x; 1.0107x over previous
//
#include <hip/hip_runtime.h>

// out[b,o,i,l] = white_table[o,i, x[b,i,o,l]]
// B=8, IN=64, OUT=64, L=2048, LUT=256
// One block per (o,i) pair; block processes all 8 batch rows so the
// (o,i) LUT row is staged into LDS exactly once (was 8x across blocks).

#define BATCH  8
#define IN_CH  64
#define OUT_CH 64
#define LEN    2048
#define LUTN   256

typedef int   i32x4 __attribute__((ext_vector_type(4)));
typedef float f32x4 __attribute__((ext_vector_type(4)));

__global__ __launch_bounds__(256) void WhiteTranspose_28406913696445_kernel(
    const int* __restrict__ x,
    const float* __restrict__ table,
    float* __restrict__ out)
{
    __shared__ float lut[LUTN];

    const int pair = blockIdx.x;             // pair = o*IN_CH + i
    const int i = pair & (IN_CH - 1);
    const int o = pair >> 6;

    // Stage this (o,i) LUT row once: 256 floats, one per thread.
    lut[threadIdx.x] = table[(size_t)pair * LUTN + threadIdx.x];
    __syncthreads();

    const size_t x_row0      = (size_t)(i * OUT_CH + o) * LEN;   // b=0 row in x
    const size_t out_row0    = (size_t)(o * IN_CH + i) * LEN;    // b=0 row in out
    const size_t x_bstride   = (size_t)IN_CH * OUT_CH * LEN;     // elems per batch
    const size_t out_bstride = (size_t)OUT_CH * IN_CH * LEN;

    // 8 batch rows x 2048 elems; 256 threads -> 2 int4 chunks per row per thread.
    #pragma unroll
    for (int b = 0; b < BATCH; ++b) {
        const i32x4* __restrict__ xin =
            (const i32x4*)(x + x_row0 + (size_t)b * x_bstride);
        f32x4* __restrict__ dst =
            (f32x4*)(out + out_row0 + (size_t)b * out_bstride);
        #pragma unroll
        for (int it = 0; it < 2; ++it) {
            const int idx = threadIdx.x + it * 256;
            const i32x4 v = __builtin_nontemporal_load(&xin[idx]);
            f32x4 r;
            r.x = lut[v.x];
            r.y = lut[v.y];
            r.z = lut[v.z];
            r.w = lut[v.w];
            __builtin_nontemporal_store(r, &dst[idx]);
        }
    }
}

extern "C" void kernel_launch(void* const* d_in, const int* in_sizes, int n_in,
                              void* d_out, int out_size, void* d_ws, size_t ws_size,
                              hipStream_t stream) {
    const int*   x     = (const int*)d_in[0];
    const float* table = (const float*)d_in[1];
    float*       out   = (float*)d_out;

    const int n_pairs = OUT_CH * IN_CH;   // 4096 blocks, 16 per CU
    WhiteTranspose_28406913696445_kernel<<<n_pairs, 256, 0, stream>>>(x, table, out);
}